// Round 1
// baseline (2888.048 us; speedup 1.0000x reference)
//
#include <hip/hip_runtime.h>

#define DD 128
#define SS 64
#define GG 256

// ---------- float<->ordered-key for atomicMax on signed floats ----------
__device__ __forceinline__ unsigned f2key(float f) {
  unsigned b = __float_as_uint(f);
  return (b & 0x80000000u) ? ~b : (b | 0x80000000u);
}
__device__ __forceinline__ float key2f(unsigned k) {
  return (k & 0x80000000u) ? __uint_as_float(k & 0x7FFFFFFFu)
                           : __uint_as_float(~k);
}

__global__ void k_init_segmax(unsigned* __restrict__ segmax) {
  segmax[threadIdx.x] = 0x007FFFFFu;  // key(-inf)
}

// ---------- K1: BN1 column stats of (sub @ W1 + b1), X1 discarded ----------
// grid N/64, block 256. Tile 64 rows x 128 cols, micro 4r x 8c.
__global__ __launch_bounds__(256) void k1_bn1stats(
    const float* __restrict__ sub, const float* __restrict__ W1,
    const float* __restrict__ b1, float* __restrict__ bn1s,
    float* __restrict__ bn1q, int N) {
  __shared__ float asub[64][68];   // pad 68: conflict-free, 16B-aligned rows
  __shared__ float bW[64][132];
  __shared__ float bn1l[256];
  int tid = threadIdx.x;
  int row0 = blockIdx.x * 64;
  bn1l[tid] = 0.f;
  for (int i = tid; i < 1024; i += 256) {  // sub tile 64x64 as float4
    int r = i >> 4, c4 = i & 15;
    *reinterpret_cast<float4*>(&asub[r][c4 * 4]) =
        *reinterpret_cast<const float4*>(&sub[(size_t)(row0 + r) * SS + c4 * 4]);
  }
  for (int i = tid; i < 2048; i += 256) {  // W1 64x128 as float4
    int r = i >> 5, c4 = i & 31;
    *reinterpret_cast<float4*>(&bW[r][c4 * 4]) =
        *reinterpret_cast<const float4*>(&W1[(size_t)r * DD + c4 * 4]);
  }
  __syncthreads();
  int rg = tid >> 4, cg = tid & 15;
  int r0 = rg * 4, c0 = cg * 8;
  float acc[4][8];
#pragma unroll
  for (int j = 0; j < 4; ++j)
#pragma unroll
    for (int i = 0; i < 8; ++i) acc[j][i] = 0.f;
  for (int k = 0; k < 64; ++k) {
    float a0 = asub[r0][k], a1v = asub[r0 + 1][k];
    float a2v = asub[r0 + 2][k], a3v = asub[r0 + 3][k];
    float4 bv0 = *reinterpret_cast<const float4*>(&bW[k][c0]);
    float4 bv1 = *reinterpret_cast<const float4*>(&bW[k][c0 + 4]);
    float bb[8] = {bv0.x, bv0.y, bv0.z, bv0.w, bv1.x, bv1.y, bv1.z, bv1.w};
#pragma unroll
    for (int i = 0; i < 8; ++i) {
      acc[0][i] = fmaf(a0, bb[i], acc[0][i]);
      acc[1][i] = fmaf(a1v, bb[i], acc[1][i]);
      acc[2][i] = fmaf(a2v, bb[i], acc[2][i]);
      acc[3][i] = fmaf(a3v, bb[i], acc[3][i]);
    }
  }
#pragma unroll
  for (int i = 0; i < 8; ++i) {
    float b1c = b1[c0 + i];
    float s = 0.f, q = 0.f;
#pragma unroll
    for (int j = 0; j < 4; ++j) {
      float x = acc[j][i] + b1c;
      s += x;
      q += x * x;
    }
    atomicAdd(&bn1l[c0 + i], s);
    atomicAdd(&bn1l[128 + c0 + i], q);
  }
  __syncthreads();
  if (tid < 128) {
    atomicAdd(&bn1s[tid], bn1l[tid]);
    atomicAdd(&bn1q[tid], bn1l[128 + tid]);
  }
}

// ---------- K1b: per-graph sum/sumsq of h + counts (batch sorted) ----------
// grid ceil(N/256), block 128 (thread = channel). Flush on graph change.
__global__ __launch_bounds__(128) void k1b_graphstats(
    const float* __restrict__ h, const int* __restrict__ batch,
    float* __restrict__ gsum, float* __restrict__ gsq,
    float* __restrict__ counts, int N) {
  __shared__ int btc[256];
  int tid = threadIdx.x;
  int row0 = blockIdx.x * 256;
  for (int i = tid; i < 256; i += 128) {
    int row = row0 + i;
    btc[i] = (row < N) ? batch[row] : -1;
  }
  __syncthreads();
  float s = 0.f, q = 0.f, cnt = 0.f;
  int gcur = -1;
  for (int r = 0; r < 256; ++r) {
    int g = btc[r];
    if (g < 0) break;
    if (g != gcur) {
      if (gcur >= 0) {
        atomicAdd(&gsum[(size_t)gcur * DD + tid], s);
        atomicAdd(&gsq[(size_t)gcur * DD + tid], q);
        if (tid == 0) atomicAdd(&counts[gcur], cnt);
      }
      gcur = g; s = 0.f; q = 0.f; cnt = 0.f;
    }
    float v = h[(size_t)(row0 + r) * DD + tid];
    s += v; q += v * v; cnt += 1.f;
  }
  if (gcur >= 0) {
    atomicAdd(&gsum[(size_t)gcur * DD + tid], s);
    atomicAdd(&gsq[(size_t)gcur * DD + tid], q);
    if (tid == 0) atomicAdd(&counts[gcur], cnt);
  }
}

// ---------- tiny finalizers ----------
__global__ void k2a_bn_final(const float* __restrict__ s, const float* __restrict__ q,
                             const float* __restrict__ gamma, const float* __restrict__ beta,
                             float* __restrict__ sc, float* __restrict__ sh, float Nf) {
  int d = threadIdx.x;
  float m = s[d] / Nf;
  float v = q[d] / Nf - m * m;
  float r = rsqrtf(v + 1e-5f);
  float scv = gamma[d] * r;
  sc[d] = scv;
  sh[d] = beta[d] - m * scv;
}

__global__ void k2b_graph_final(const float* __restrict__ gsum, const float* __restrict__ gsq,
                                const float* __restrict__ counts, float* __restrict__ gmean,
                                float* __restrict__ grstd) {
  int g = blockIdx.x, d = threadIdx.x;
  float c = counts[g];
  float cf = c > 1.f ? c : 1.f;
  size_t idx = (size_t)g * DD + d;
  float m = gsum[idx] / cf;
  float v = gsq[idx] / cf - m * m;
  float sd = sqrtf(fmaxf(v, 1e-8f));
  gmean[idx] = m;
  grstd[idx] = 1.f / (sd + 1e-8f);
}

// ---------- K3: se -> gate -> h_fused/h_dev -> z_pre (+BN2 partials) ----------
// grid N/32, block 256. Tile 32 rows x 128 cols, micro 2r x 8c. ~60KB LDS.
__global__ __launch_bounds__(256) void k3_main(
    const float* __restrict__ h, const float* __restrict__ sub,
    const int* __restrict__ batch, const float* __restrict__ W1,
    const float* __restrict__ b1, const float* __restrict__ sc1,
    const float* __restrict__ sh1, const float* __restrict__ Wg,
    const float* __restrict__ bg, const float* __restrict__ Ws1,
    const float* __restrict__ bs1, const float* __restrict__ gmean,
    const float* __restrict__ grstd, float* __restrict__ hfused,
    float* __restrict__ zpre, float* __restrict__ bn2s,
    float* __restrict__ bn2q, int N) {
  __shared__ float a1[32][132];   // h, later h_fused
  __shared__ float a2[32][132];   // se, later h_dev
  __shared__ float bW[32][132];   // streamed weight chunk (BK=32)
  __shared__ float asub[32][68];
  __shared__ int bt[32];
  __shared__ float bn2l[256];
  int tid = threadIdx.x;
  int row0 = blockIdx.x * 32;
  bn2l[tid] = 0.f;
  for (int i = tid; i < 1024; i += 256) {  // h tile 32x128
    int r = i >> 5, c4 = i & 31;
    *reinterpret_cast<float4*>(&a1[r][c4 * 4]) =
        *reinterpret_cast<const float4*>(&h[(size_t)(row0 + r) * DD + c4 * 4]);
  }
  for (int i = tid; i < 512; i += 256) {  // sub tile 32x64
    int r = i >> 4, c4 = i & 15;
    *reinterpret_cast<float4*>(&asub[r][c4 * 4]) =
        *reinterpret_cast<const float4*>(&sub[(size_t)(row0 + r) * SS + c4 * 4]);
  }
  if (tid < 32) bt[tid] = batch[row0 + tid];
  __syncthreads();

  int rg = tid >> 4, cg = tid & 15;
  int r0 = rg * 2, c0 = cg * 8;
  float acc[2][8];

  // ---- Phase A: X1 = sub@W1 ; se = relu(X1*sc1+sh1) -> a2
#pragma unroll
  for (int j = 0; j < 2; ++j)
#pragma unroll
    for (int i = 0; i < 8; ++i) acc[j][i] = 0.f;
  for (int kb = 0; kb < 64; kb += 32) {
    __syncthreads();
    for (int i = tid; i < 1024; i += 256) {
      int r = i >> 5, c4 = i & 31;
      *reinterpret_cast<float4*>(&bW[r][c4 * 4]) =
          *reinterpret_cast<const float4*>(&W1[(size_t)(kb + r) * DD + c4 * 4]);
    }
    __syncthreads();
#pragma unroll 4
    for (int k = 0; k < 32; ++k) {
      float a0 = asub[r0][kb + k], a1v = asub[r0 + 1][kb + k];
      float4 b0 = *reinterpret_cast<const float4*>(&bW[k][c0]);
      float4 b1v = *reinterpret_cast<const float4*>(&bW[k][c0 + 4]);
      float bb[8] = {b0.x, b0.y, b0.z, b0.w, b1v.x, b1v.y, b1v.z, b1v.w};
#pragma unroll
      for (int i = 0; i < 8; ++i) {
        acc[0][i] = fmaf(a0, bb[i], acc[0][i]);
        acc[1][i] = fmaf(a1v, bb[i], acc[1][i]);
      }
    }
  }
#pragma unroll
  for (int i = 0; i < 8; ++i) {
    int c = c0 + i;
    float s1 = sc1[c], h1 = sh1[c], b1c = b1[c];
#pragma unroll
    for (int j = 0; j < 2; ++j) {
      float x = acc[j][i] + b1c;
      float se = fmaf(x, s1, h1);
      a2[r0 + j][c] = se > 0.f ? se : 0.f;   // own element; next sync orders it
    }
  }

  // ---- Phase B: gate = sigmoid([h|se]@Wg + bg)
#pragma unroll
  for (int j = 0; j < 2; ++j)
#pragma unroll
    for (int i = 0; i < 8; ++i) acc[j][i] = 0.f;
  for (int kb = 0; kb < 256; kb += 32) {
    __syncthreads();
    for (int i = tid; i < 1024; i += 256) {
      int r = i >> 5, c4 = i & 31;
      *reinterpret_cast<float4*>(&bW[r][c4 * 4]) =
          *reinterpret_cast<const float4*>(&Wg[(size_t)(kb + r) * DD + c4 * 4]);
    }
    __syncthreads();
    const float* srcA = (kb < 128) ? &a1[0][0] : &a2[0][0];
    int kloc = kb & 127;
#pragma unroll 4
    for (int k = 0; k < 32; ++k) {
      float a0 = srcA[(size_t)r0 * 132 + kloc + k];
      float a1v = srcA[(size_t)(r0 + 1) * 132 + kloc + k];
      float4 b0 = *reinterpret_cast<const float4*>(&bW[k][c0]);
      float4 b1v = *reinterpret_cast<const float4*>(&bW[k][c0 + 4]);
      float bb[8] = {b0.x, b0.y, b0.z, b0.w, b1v.x, b1v.y, b1v.z, b1v.w};
#pragma unroll
      for (int i = 0; i < 8; ++i) {
        acc[0][i] = fmaf(a0, bb[i], acc[0][i]);
        acc[1][i] = fmaf(a1v, bb[i], acc[1][i]);
      }
    }
  }
  // gate/fuse into registers (reads only; writes deferred past barrier)
  float hfv[2][8], hdv[2][8];
  int gA = bt[r0], gB = bt[r0 + 1];
#pragma unroll
  for (int i = 0; i < 8; ++i) {
    int c = c0 + i;
    float bgc = bg[c];
    float mA = gmean[(size_t)gA * DD + c], rA = grstd[(size_t)gA * DD + c];
    float mB = gmean[(size_t)gB * DD + c], rB = grstd[(size_t)gB * DD + c];
    float hv0 = a1[r0][c], hv1 = a1[r0 + 1][c];
    float se0 = a2[r0][c], se1 = a2[r0 + 1][c];
    float g0 = 1.f / (1.f + expf(-(acc[0][i] + bgc)));
    float g1v = 1.f / (1.f + expf(-(acc[1][i] + bgc)));
    hfv[0][i] = fmaf(g0, se0, hv0);
    hfv[1][i] = fmaf(g1v, se1, hv1);
    hdv[0][i] = (hv0 - mA) * rA;
    hdv[1][i] = (hv1 - mB) * rB;
  }
  __syncthreads();  // all Phase-B LDS reads complete before overwrite
#pragma unroll
  for (int j = 0; j < 2; ++j) {
#pragma unroll
    for (int i = 0; i < 8; ++i) {
      a1[r0 + j][c0 + i] = hfv[j][i];
      a2[r0 + j][c0 + i] = hdv[j][i];
    }
    float4 st0 = {hfv[j][0], hfv[j][1], hfv[j][2], hfv[j][3]};
    float4 st1 = {hfv[j][4], hfv[j][5], hfv[j][6], hfv[j][7]};
    *reinterpret_cast<float4*>(&hfused[(size_t)(row0 + r0 + j) * DD + c0]) = st0;
    *reinterpret_cast<float4*>(&hfused[(size_t)(row0 + r0 + j) * DD + c0 + 4]) = st1;
  }

  // ---- Phase C: z_pre = [h_fused|h_dev]@Ws1 + bs1 (+BN2 partial stats)
#pragma unroll
  for (int j = 0; j < 2; ++j)
#pragma unroll
    for (int i = 0; i < 8; ++i) acc[j][i] = 0.f;
  for (int kb = 0; kb < 256; kb += 32) {
    __syncthreads();
    for (int i = tid; i < 1024; i += 256) {
      int r = i >> 5, c4 = i & 31;
      *reinterpret_cast<float4*>(&bW[r][c4 * 4]) =
          *reinterpret_cast<const float4*>(&Ws1[(size_t)(kb + r) * DD + c4 * 4]);
    }
    __syncthreads();
    const float* srcA = (kb < 128) ? &a1[0][0] : &a2[0][0];
    int kloc = kb & 127;
#pragma unroll 4
    for (int k = 0; k < 32; ++k) {
      float a0 = srcA[(size_t)r0 * 132 + kloc + k];
      float a1v = srcA[(size_t)(r0 + 1) * 132 + kloc + k];
      float4 b0 = *reinterpret_cast<const float4*>(&bW[k][c0]);
      float4 b1v = *reinterpret_cast<const float4*>(&bW[k][c0 + 4]);
      float bb[8] = {b0.x, b0.y, b0.z, b0.w, b1v.x, b1v.y, b1v.z, b1v.w};
#pragma unroll
      for (int i = 0; i < 8; ++i) {
        acc[0][i] = fmaf(a0, bb[i], acc[0][i]);
        acc[1][i] = fmaf(a1v, bb[i], acc[1][i]);
      }
    }
  }
  float zp[2][8];
#pragma unroll
  for (int i = 0; i < 8; ++i) {
    float bsc = bs1[c0 + i];
    zp[0][i] = acc[0][i] + bsc;
    zp[1][i] = acc[1][i] + bsc;
    atomicAdd(&bn2l[c0 + i], zp[0][i] + zp[1][i]);
    atomicAdd(&bn2l[128 + c0 + i], zp[0][i] * zp[0][i] + zp[1][i] * zp[1][i]);
  }
#pragma unroll
  for (int j = 0; j < 2; ++j) {
    float4 st0 = {zp[j][0], zp[j][1], zp[j][2], zp[j][3]};
    float4 st1 = {zp[j][4], zp[j][5], zp[j][6], zp[j][7]};
    *reinterpret_cast<float4*>(&zpre[(size_t)(row0 + r0 + j) * DD + c0]) = st0;
    *reinterpret_cast<float4*>(&zpre[(size_t)(row0 + r0 + j) * DD + c0 + 4]) = st1;
  }
  __syncthreads();
  if (tid < 128) {
    atomicAdd(&bn2s[tid], bn2l[tid]);
    atomicAdd(&bn2q[tid], bn2l[128 + tid]);
  }
}

// ---------- K5: logit = relu(bn2(z_pre)) . Ws2 + bs2 ; segment max ----------
// grid ceil(N/256), block 256 (4 waves, 64 rows each). Wave-reduce over 64 lanes.
__global__ __launch_bounds__(256) void k5_logit(
    const float* __restrict__ zpre, const int* __restrict__ batch,
    const float* __restrict__ sc2, const float* __restrict__ sh2,
    const float* __restrict__ Ws2, const float* __restrict__ bs2,
    float* __restrict__ logit, unsigned* __restrict__ segmax, int N) {
  int tid = threadIdx.x;
  int wave = tid >> 6, lane = tid & 63;
  int base = blockIdx.x * 256 + wave * 64;
  float s2a = sc2[lane], s2b = sc2[lane + 64];
  float h2a = sh2[lane], h2b = sh2[lane + 64];
  float w2a = Ws2[lane], w2b = Ws2[lane + 64];
  float b2 = bs2[0];
  for (int r = 0; r < 64; ++r) {
    int row = base + r;
    if (row >= N) break;
    float z0 = zpre[(size_t)row * DD + lane];
    float z1 = zpre[(size_t)row * DD + 64 + lane];
    z0 = fmaf(z0, s2a, h2a); z0 = z0 > 0.f ? z0 : 0.f;
    z1 = fmaf(z1, s2b, h2b); z1 = z1 > 0.f ? z1 : 0.f;
    float p = z0 * w2a + z1 * w2b;
#pragma unroll
    for (int off = 32; off > 0; off >>= 1) p += __shfl_down(p, off);
    if (lane == 0) {
      float lg = p + b2;
      logit[row] = lg;
      atomicMax(&segmax[batch[row]], f2key(lg));
    }
  }
}

// ---------- K6: e = exp(logit-max); accumulate denom and sum(hf*e) ----------
// grid ceil(N/256), block 128 (thread = channel). Flush on graph change.
__global__ __launch_bounds__(128) void k6_accum(
    const float* __restrict__ hf, const float* __restrict__ logit,
    const int* __restrict__ batch, const unsigned* __restrict__ segmax,
    float* __restrict__ denom, float* __restrict__ wf, int N) {
  __shared__ float eb[256];
  __shared__ int btc[256];
  int tid = threadIdx.x;
  int row0 = blockIdx.x * 256;
  for (int i = tid; i < 256; i += 128) {
    int row = row0 + i;
    if (row < N) {
      btc[i] = batch[row];
      eb[i] = logit[row];
    } else {
      btc[i] = -1;
    }
  }
  __syncthreads();
  for (int i = tid; i < 256; i += 128) {
    if (btc[i] >= 0) eb[i] = expf(eb[i] - key2f(segmax[btc[i]]));
  }
  __syncthreads();
  float acc = 0.f, dsum = 0.f;
  int gcur = -1;
  for (int r = 0; r < 256; ++r) {
    int g = btc[r];
    if (g < 0) break;
    if (g != gcur) {
      if (gcur >= 0) {
        atomicAdd(&wf[(size_t)gcur * DD + tid], acc);
        if (tid == 0) atomicAdd(&denom[gcur], dsum);
      }
      gcur = g; acc = 0.f; dsum = 0.f;
    }
    float e = eb[r];
    acc = fmaf(hf[(size_t)(row0 + r) * DD + tid], e, acc);
    dsum += e;
  }
  if (gcur >= 0) {
    atomicAdd(&wf[(size_t)gcur * DD + tid], acc);
    if (tid == 0) atomicAdd(&denom[gcur], dsum);
  }
}

// ---------- K7: out = alpha*wf/denom + (1-alpha)*gmean ----------
__global__ void k7_out(const float* __restrict__ wf, const float* __restrict__ denom,
                       const float* __restrict__ gmean, const float* __restrict__ mix,
                       float* __restrict__ out) {
  int g = blockIdx.x, d = threadIdx.x;
  float alpha = 1.f / (1.f + expf(-mix[0]));
  float dn = denom[g];
  size_t idx = (size_t)g * DD + d;
  float w = (dn > 0.f) ? wf[idx] / dn : 0.f;
  out[idx] = alpha * w + (1.f - alpha) * gmean[idx];
}

extern "C" void kernel_launch(void* const* d_in, const int* in_sizes, int n_in,
                              void* d_out, int out_size, void* d_ws, size_t ws_size,
                              hipStream_t stream) {
  const float* h   = (const float*)d_in[0];
  const float* sub = (const float*)d_in[1];
  const int* batch = (const int*)d_in[2];
  const float* W1  = (const float*)d_in[3];
  const float* b1  = (const float*)d_in[4];
  const float* g1  = (const float*)d_in[5];
  const float* be1 = (const float*)d_in[6];
  const float* Wg  = (const float*)d_in[7];
  const float* bg  = (const float*)d_in[8];
  const float* Ws1 = (const float*)d_in[9];
  const float* bs1 = (const float*)d_in[10];
  const float* g2  = (const float*)d_in[11];
  const float* be2 = (const float*)d_in[12];
  const float* Ws2 = (const float*)d_in[13];
  const float* bs2 = (const float*)d_in[14];
  const float* mix = (const float*)d_in[15];
  float* out = (float*)d_out;
  const int N = in_sizes[0] / DD;  // 400000 (divisible by 64 and 32)

  // ---- workspace layout (fp32) ----
  float* ws = (float*)d_ws;
  size_t off = 0;
  float* hf    = ws + off; off += (size_t)N * DD;   // h_fused
  float* zp    = ws + off; off += (size_t)N * DD;   // z_pre
  float* logit = ws + off; off += (size_t)N;
  float* zbase = ws + off;                           // start of zeroed region
  float* gsum  = ws + off; off += (size_t)GG * DD;
  float* gsq   = ws + off; off += (size_t)GG * DD;
  float* wf    = ws + off; off += (size_t)GG * DD;
  float* bn1s  = ws + off; off += 128;
  float* bn1q  = ws + off; off += 128;
  float* bn2s  = ws + off; off += 128;
  float* bn2q  = ws + off; off += 128;
  float* counts = ws + off; off += GG;
  float* denom  = ws + off; off += GG;
  size_t zcount = (size_t)(ws + off - zbase);
  float* gmean = ws + off; off += (size_t)GG * DD;
  float* grstd = ws + off; off += (size_t)GG * DD;
  float* sc1 = ws + off; off += 128;
  float* sh1 = ws + off; off += 128;
  float* sc2 = ws + off; off += 128;
  float* sh2 = ws + off; off += 128;
  unsigned* segmax = (unsigned*)(ws + off); off += GG;

  hipMemsetAsync(zbase, 0, zcount * sizeof(float), stream);
  k_init_segmax<<<1, GG, 0, stream>>>(segmax);

  k1_bn1stats<<<N / 64, 256, 0, stream>>>(sub, W1, b1, bn1s, bn1q, N);
  k1b_graphstats<<<(N + 255) / 256, 128, 0, stream>>>(h, batch, gsum, gsq, counts, N);
  k2a_bn_final<<<1, 128, 0, stream>>>(bn1s, bn1q, g1, be1, sc1, sh1, (float)N);
  k2b_graph_final<<<GG, 128, 0, stream>>>(gsum, gsq, counts, gmean, grstd);

  k3_main<<<N / 32, 256, 0, stream>>>(h, sub, batch, W1, b1, sc1, sh1, Wg, bg,
                                      Ws1, bs1, gmean, grstd, hf, zp, bn2s, bn2q, N);

  k2a_bn_final<<<1, 128, 0, stream>>>(bn2s, bn2q, g2, be2, sc2, sh2, (float)N);
  k5_logit<<<(N + 255) / 256, 256, 0, stream>>>(zp, batch, sc2, sh2, Ws2, bs2,
                                                logit, segmax, N);
  k6_accum<<<(N + 255) / 256, 128, 0, stream>>>(hf, logit, batch, segmax, denom, wf, N);
  k7_out<<<GG, 128, 0, stream>>>(wf, denom, gmean, mix, out);
}